// Round 1
// baseline (7973.244 us; speedup 1.0000x reference)
//
#include <hip/hip_runtime.h>
#include <hip/hip_bf16.h>
#include <stdint.h>

#define HID 1024
#define VOC 1024
#define BB  32
#define TT  512
#define G4  4096   // 4*HID

typedef float f32x4 __attribute__((ext_vector_type(4)));
typedef short bf16x8 __attribute__((ext_vector_type(8)));

static __device__ __forceinline__ unsigned short f2bf(float f) {
    union { float f; unsigned u; } v; v.f = f;
    unsigned r = (v.u + 0x7FFFu + ((v.u >> 16) & 1u)) >> 16;  // RTNE
    return (unsigned short)r;
}
static __device__ __forceinline__ float bf2f(unsigned short s) {
    union { unsigned u; float f; } v; v.u = ((unsigned)s) << 16;
    return v.f;
}

// ---------------- f32 -> bf16 conversion, 4 elems/thread ----------------
__global__ void cvt_f32_bf16(const float* __restrict__ in,
                             unsigned short* __restrict__ out, int n4) {
    int i = blockIdx.x * blockDim.x + threadIdx.x;
    if (i >= n4) return;
    float4 v = ((const float4*)in)[i];
    ushort4 o;
    o.x = f2bf(v.x); o.y = f2bf(v.y); o.z = f2bf(v.z); o.w = f2bf(v.w);
    ((ushort4*)out)[i] = o;
}

// ---------------- Phase 1: x_proj GEMM ----------------
// XP[m][n] = sum_k A[m][k]*W[n][k] + b_ih[n] + b_hh[n], stored bf16.
// A: [16384][1024] bf16, W: [4096][1024] bf16. 128x128 tile, BK=64,
// 4 waves (2x2 of 64x64), global_load_lds staging (m97 structure).
__global__ __launch_bounds__(256) void gemm_xproj(
    const unsigned short* __restrict__ A, const unsigned short* __restrict__ W,
    const float* __restrict__ bih, const float* __restrict__ bhh,
    unsigned short* __restrict__ XP)
{
    __shared__ unsigned short As[128 * 64];
    __shared__ unsigned short Bs[128 * 64];
    const int tid  = threadIdx.x;
    const int lane = tid & 63;
    const int wid  = tid >> 6;
    const int mt = blockIdx.x & 127;   // 128 M-tiles
    const int nt = blockIdx.x >> 7;    // 32  N-tiles
    const long m0 = (long)mt * 128;
    const long n0 = (long)nt * 128;

    const int wr = wid >> 1, wc = wid & 1;
    const int rl = lane & 15;            // row-in-frag
    const int kl = (lane >> 4) * 8;      // k-offset-in-frag

    f32x4 acc[4][4] = {};

    for (int kt = 0; kt < 16; ++kt) {
#pragma unroll
        for (int it = 0; it < 4; ++it) {
            int slot = it * 256 + tid;
            int r = slot >> 3, c8 = slot & 7;
            const unsigned short* ga = A + (m0 + r) * 1024 + kt * 64 + c8 * 8;
            const unsigned short* gb = W + (n0 + r) * 1024 + kt * 64 + c8 * 8;
            char* la = (char*)As + (it * 256 + wid * 64) * 16;  // wave-uniform base
            char* lb = (char*)Bs + (it * 256 + wid * 64) * 16;
            __builtin_amdgcn_global_load_lds(
                (const __attribute__((address_space(1))) void*)ga,
                (__attribute__((address_space(3))) void*)la, 16, 0, 0);
            __builtin_amdgcn_global_load_lds(
                (const __attribute__((address_space(1))) void*)gb,
                (__attribute__((address_space(3))) void*)lb, 16, 0, 0);
        }
        __syncthreads();
#pragma unroll
        for (int kk = 0; kk < 2; ++kk) {
            bf16x8 af[4], bfr[4];
#pragma unroll
            for (int i = 0; i < 4; ++i) {
                int ar = wr * 64 + i * 16 + rl;
                int br = wc * 64 + i * 16 + rl;
                af[i]  = *(const bf16x8*)(As + ar * 64 + kk * 32 + kl);
                bfr[i] = *(const bf16x8*)(Bs + br * 64 + kk * 32 + kl);
            }
#pragma unroll
            for (int i = 0; i < 4; ++i)
#pragma unroll
                for (int j = 0; j < 4; ++j)
                    acc[i][j] = __builtin_amdgcn_mfma_f32_16x16x32_bf16(
                        af[i], bfr[j], acc[i][j], 0, 0, 0);
        }
        __syncthreads();
    }
    // epilogue: D row = m (batch*T+t), col = n; add biases; store bf16
#pragma unroll
    for (int i = 0; i < 4; ++i)
#pragma unroll
        for (int j = 0; j < 4; ++j)
#pragma unroll
            for (int r = 0; r < 4; ++r) {
                long row = m0 + wr * 64 + i * 16 + (lane >> 4) * 4 + r;
                long col = n0 + wc * 64 + j * 16 + (lane & 15);
                float v = acc[i][j][r] + bih[col] + bhh[col];
                XP[row * 4096 + col] = f2bf(v);
            }
}

// ---------------- Phase 2: one timestep ----------------
// grid 64 blocks (hidden slice of 16 each), 4 waves = gate groups i,f,g,o.
// Per wave: [32 x 16] = h[32x1024] @ W_hh_slice^T via 2x32 MFMAs, frags
// straight from L2 (h is 64KB, W_hh row read once per step).
__global__ __launch_bounds__(256) void lstm_step(
    const unsigned short* __restrict__ Whh,   // [4096][1024] bf16
    const unsigned short* __restrict__ XP,    // [16384][4096] bf16
    const unsigned short* __restrict__ h_in,  // [32][1024] bf16
    unsigned short* __restrict__ h_out,       // [32][1024] bf16
    float* __restrict__ c,                    // [32][1024] f32 (block-private slice)
    float* __restrict__ out,                  // [32][512][1024] f32
    int t)
{
    const int tid  = threadIdx.x;
    const int lane = tid & 63;
    const int g    = tid >> 6;            // gate group
    const int j0   = blockIdx.x * 16;     // hidden slice

    __shared__ float gtile[4][32][16];    // 8 KB

    const int nl = lane & 15;
    const int kl = (lane >> 4) * 8;
    f32x4 acc0 = {}, acc1 = {};
    const unsigned short* wrow = Whh + (long)(g * 1024 + j0 + nl) * 1024 + kl;
    const unsigned short* ha   = h_in + (long)nl * 1024 + kl;         // batches 0..15
    const unsigned short* hb   = h_in + (long)(16 + nl) * 1024 + kl;  // batches 16..31
#pragma unroll 8
    for (int kt = 0; kt < 32; ++kt) {
        bf16x8 bfr = *(const bf16x8*)(wrow + kt * 32);
        bf16x8 a0  = *(const bf16x8*)(ha + kt * 32);
        bf16x8 a1  = *(const bf16x8*)(hb + kt * 32);
        acc0 = __builtin_amdgcn_mfma_f32_16x16x32_bf16(a0, bfr, acc0, 0, 0, 0);
        acc1 = __builtin_amdgcn_mfma_f32_16x16x32_bf16(a1, bfr, acc1, 0, 0, 0);
    }
    const int jj = lane & 15;
#pragma unroll
    for (int r = 0; r < 4; ++r) {
        int b0 = (lane >> 4) * 4 + r;
        gtile[g][b0][jj] = acc0[r] +
            bf2f(XP[((long)b0 * 512 + t) * 4096 + g * 1024 + j0 + jj]);
        gtile[g][b0 + 16][jj] = acc1[r] +
            bf2f(XP[((long)(b0 + 16) * 512 + t) * 4096 + g * 1024 + j0 + jj]);
    }
    __syncthreads();
#pragma unroll
    for (int p = tid; p < 512; p += 256) {
        int b = p >> 4, j2 = p & 15;
        int j = j0 + j2;
        float ig = gtile[0][b][j2], fg = gtile[1][b][j2];
        float gg = gtile[2][b][j2], og = gtile[3][b][j2];
        ig = 1.f / (1.f + __expf(-ig));
        fg = 1.f / (1.f + __expf(-fg));
        gg = tanhf(gg);
        og = 1.f / (1.f + __expf(-og));
        float cold = c[b * 1024 + j];
        float cn = fg * cold + ig * gg;
        float hn = og * tanhf(cn);
        c[b * 1024 + j] = cn;
        out[((long)b * 512 + t) * 1024 + j] = hn;
        h_out[b * 1024 + j] = f2bf(hn);
    }
}

extern "C" void kernel_launch(void* const* d_in, const int* in_sizes, int n_in,
                              void* d_out, int out_size, void* d_ws, size_t ws_size,
                              hipStream_t stream)
{
    const float* x   = (const float*)d_in[0];
    const float* Wih = (const float*)d_in[1];
    const float* Whh = (const float*)d_in[2];
    const float* bih = (const float*)d_in[3];
    const float* bhh = (const float*)d_in[4];
    float* out = (float*)d_out;

    char* ws = (char*)d_ws;
    size_t off = 0;
    auto alloc = [&](size_t bytes) {
        char* p = ws + off;
        off = (off + bytes + 255) & ~(size_t)255;
        return p;
    };
    unsigned short* x_bf   = (unsigned short*)alloc((size_t)BB * TT * VOC * 2); // 33.6 MB
    unsigned short* wih_bf = (unsigned short*)alloc((size_t)G4 * VOC * 2);      //  8.4 MB
    unsigned short* whh_bf = (unsigned short*)alloc((size_t)G4 * HID * 2);      //  8.4 MB
    unsigned short* xp     = (unsigned short*)alloc((size_t)BB * TT * G4 * 2);  // 134 MB
    unsigned short* hbuf0  = (unsigned short*)alloc((size_t)BB * HID * 2);
    unsigned short* hbuf1  = (unsigned short*)alloc((size_t)BB * HID * 2);
    float* cbuf            = (float*)alloc((size_t)BB * HID * 4);

    // conversions to bf16
    int n4x = BB * TT * VOC / 4;
    cvt_f32_bf16<<<(n4x + 255) / 256, 256, 0, stream>>>(x, x_bf, n4x);
    int n4w = G4 * VOC / 4;
    cvt_f32_bf16<<<(n4w + 255) / 256, 256, 0, stream>>>(Wih, wih_bf, n4w);
    cvt_f32_bf16<<<(n4w + 255) / 256, 256, 0, stream>>>(Whh, whh_bf, n4w);

    // x_proj big GEMM (adds both biases)
    gemm_xproj<<<4096, 256, 0, stream>>>(x_bf, wih_bf, bih, bhh, xp);

    // init recurrent state (ws is poisoned 0xAA before every launch)
    hipMemsetAsync(hbuf0, 0, (size_t)BB * HID * 2, stream);
    hipMemsetAsync(cbuf, 0, (size_t)BB * HID * 4, stream);

    // sequential scan: stream order serializes steps; h double-buffered
    for (int t = 0; t < TT; ++t) {
        const unsigned short* hi = (t & 1) ? hbuf1 : hbuf0;
        unsigned short* ho = (t & 1) ? hbuf0 : hbuf1;
        lstm_step<<<64, 256, 0, stream>>>(whh_bf, xp, hi, ho, cbuf, out, t);
    }
}

// Round 2
// 4189.708 us; speedup vs baseline: 1.9031x; 1.9031x over previous
//
#include <hip/hip_runtime.h>
#include <hip/hip_bf16.h>
#include <stdint.h>

#define HID 1024
#define VOC 1024
#define BB  32
#define TT  512
#define G4  4096   // 4*HID
#define NBLK 64

typedef float f32x4 __attribute__((ext_vector_type(4)));
typedef short bf16x8 __attribute__((ext_vector_type(8)));
typedef unsigned short u16x8 __attribute__((ext_vector_type(8)));

static __device__ __forceinline__ unsigned short f2bf(float f) {
    union { float f; unsigned u; } v; v.f = f;
    unsigned r = (v.u + 0x7FFFu + ((v.u >> 16) & 1u)) >> 16;  // RTNE
    return (unsigned short)r;
}
static __device__ __forceinline__ float bf2f(unsigned short s) {
    union { unsigned u; float f; } v; v.u = ((unsigned)s) << 16;
    return v.f;
}

// ---------------- f32 -> bf16 conversion, 4 elems/thread ----------------
__global__ void cvt_f32_bf16(const float* __restrict__ in,
                             unsigned short* __restrict__ out, int n4) {
    int i = blockIdx.x * blockDim.x + threadIdx.x;
    if (i >= n4) return;
    float4 v = ((const float4*)in)[i];
    ushort4 o;
    o.x = f2bf(v.x); o.y = f2bf(v.y); o.z = f2bf(v.z); o.w = f2bf(v.w);
    ((ushort4*)out)[i] = o;
}

// ---------------- Phase 1: x_proj GEMM ----------------
// XP[t][b][n] = sum_k x[b][t][k]*W_ih[n][k] + b_ih[n] + b_hh[n], bf16.
// Note output relayout to [T][B][4H] so the scan reads contiguous chunks.
__global__ __launch_bounds__(256) void gemm_xproj(
    const unsigned short* __restrict__ A, const unsigned short* __restrict__ W,
    const float* __restrict__ bih, const float* __restrict__ bhh,
    unsigned short* __restrict__ XP)
{
    __shared__ unsigned short As[128 * 64];
    __shared__ unsigned short Bs[128 * 64];
    const int tid  = threadIdx.x;
    const int lane = tid & 63;
    const int wid  = tid >> 6;
    const int mt = blockIdx.x & 127;   // 128 M-tiles
    const int nt = blockIdx.x >> 7;    // 32  N-tiles
    const long m0 = (long)mt * 128;
    const long n0 = (long)nt * 128;

    const int wr = wid >> 1, wc = wid & 1;
    const int rl = lane & 15;
    const int kl = (lane >> 4) * 8;

    f32x4 acc[4][4] = {};

    for (int kt = 0; kt < 16; ++kt) {
#pragma unroll
        for (int it = 0; it < 4; ++it) {
            int slot = it * 256 + tid;
            int r = slot >> 3, c8 = slot & 7;
            const unsigned short* ga = A + (m0 + r) * 1024 + kt * 64 + c8 * 8;
            const unsigned short* gb = W + (n0 + r) * 1024 + kt * 64 + c8 * 8;
            char* la = (char*)As + (it * 256 + wid * 64) * 16;
            char* lb = (char*)Bs + (it * 256 + wid * 64) * 16;
            __builtin_amdgcn_global_load_lds(
                (const __attribute__((address_space(1))) void*)ga,
                (__attribute__((address_space(3))) void*)la, 16, 0, 0);
            __builtin_amdgcn_global_load_lds(
                (const __attribute__((address_space(1))) void*)gb,
                (__attribute__((address_space(3))) void*)lb, 16, 0, 0);
        }
        __syncthreads();
#pragma unroll
        for (int kk = 0; kk < 2; ++kk) {
            bf16x8 af[4], bfr[4];
#pragma unroll
            for (int i = 0; i < 4; ++i) {
                int ar = wr * 64 + i * 16 + rl;
                int br = wc * 64 + i * 16 + rl;
                af[i]  = *(const bf16x8*)(As + ar * 64 + kk * 32 + kl);
                bfr[i] = *(const bf16x8*)(Bs + br * 64 + kk * 32 + kl);
            }
#pragma unroll
            for (int i = 0; i < 4; ++i)
#pragma unroll
                for (int j = 0; j < 4; ++j)
                    acc[i][j] = __builtin_amdgcn_mfma_f32_16x16x32_bf16(
                        af[i], bfr[j], acc[i][j], 0, 0, 0);
        }
        __syncthreads();
    }
    // epilogue: m-row = b*512+t  ->  XP row = t*32+b  (relayout)
#pragma unroll
    for (int i = 0; i < 4; ++i)
#pragma unroll
        for (int j = 0; j < 4; ++j)
#pragma unroll
            for (int r = 0; r < 4; ++r) {
                long row = m0 + wr * 64 + i * 16 + (lane >> 4) * 4 + r;
                long col = n0 + wc * 64 + j * 16 + (lane & 15);
                long orow = (row & 511) * 32 + (row >> 9);
                float v = acc[i][j][r] + bih[col] + bhh[col];
                XP[orow * 4096 + col] = f2bf(v);
            }
}

// ---------------- Phase 2: persistent scan over all 512 timesteps ----------------
// 64 blocks x 512 threads (8 waves). Block owns hidden slice j0 = blockIdx.x*16
// across all 4 gates. Wave w = (bh, kq): batches bh*16.., K-quarter kq*256..,
// all 4 gates (A-frag reused across the 4 gate MFMAs; W_hh in 128 VGPRs/wave,
// loaded once). h staged in LDS per step, XOR-swizzled. c lives in a register.
// One flag-based grid barrier per step (all 64 blocks co-resident: 1 block/CU).
__global__ __launch_bounds__(512, 2) void lstm_scan(
    const unsigned short* __restrict__ Whh,   // [4096][1024] bf16
    const unsigned short* __restrict__ XP,    // [512][32][4096] bf16
    unsigned short* __restrict__ h0,          // [32][1024] bf16 (zeroed)
    unsigned short* __restrict__ h1,          // [32][1024] bf16
    float* __restrict__ out,                  // [32][512][1024] f32
    int* __restrict__ sync)                   // [0]=arrive, [1]=go (zeroed)
{
    __shared__ unsigned short Hs[32 * 1024];   // 64KB, swizzled
    __shared__ float part[8][4][16][16];       // 32KB partial gate sums

    const int tid  = threadIdx.x;
    const int lane = tid & 63;
    const int w    = tid >> 6;     // wave 0..7
    const int bh   = w >> 2;       // batch half
    const int kq   = w & 3;        // K quarter
    const int j0   = blockIdx.x * 16;

    // ---- W_hh -> registers (once). wreg[g][kt]: col j0+(lane&15),
    //      k = kq*256 + kt*32 + (lane>>4)*8
    bf16x8 wreg[4][8];
    {
        const int nl = lane & 15, kl = (lane >> 4) * 8;
#pragma unroll
        for (int g = 0; g < 4; ++g) {
            const unsigned short* wr =
                Whh + (long)(g * 1024 + j0 + nl) * 1024 + kq * 256 + kl;
#pragma unroll
            for (int kt = 0; kt < 8; ++kt)
                wreg[g][kt] = *(const bf16x8*)(wr + kt * 32);
        }
    }

    // epilogue identity: thread owns (eb, j0+ej); c state in register
    const int eb = tid >> 4;       // batch 0..31
    const int ej = tid & 15;
    float creg = 0.f;

    for (int t = 0; t < TT; ++t) {
        const unsigned short* hin = (t & 1) ? h1 : h0;
        unsigned short* hout      = (t & 1) ? h0 : h1;

        // ---- stage h_prev -> LDS (64KB), swizzle byte ^= (row&7)<<4
#pragma unroll
        for (int i = 0; i < 8; ++i) {
            int gi  = tid + i * 512;          // 16B granule id
            int row = gi >> 7, kc = gi & 127;
            u16x8 v = *(const u16x8*)(hin + row * 1024 + kc * 8);
            int byte = (row * 2048 + kc * 16) ^ ((row & 7) << 4);
            *(u16x8*)((char*)Hs + byte) = v;
        }
        __syncthreads();

        // ---- GEMM: 8 kt-steps, 4 gates each, A-frag shared in-register
        f32x4 acc[4] = {};
        {
            const int arow  = bh * 16 + (lane & 15);
            const int kbase = kq * 256 + (lane >> 4) * 8;
            const int swz   = (arow & 7) << 4;
#pragma unroll
            for (int kt = 0; kt < 8; ++kt) {
                bf16x8 af = *(const bf16x8*)((char*)Hs +
                    ((arow * 2048 + (kbase + kt * 32) * 2) ^ swz));
                acc[0] = __builtin_amdgcn_mfma_f32_16x16x32_bf16(af, wreg[0][kt], acc[0], 0, 0, 0);
                acc[1] = __builtin_amdgcn_mfma_f32_16x16x32_bf16(af, wreg[1][kt], acc[1], 0, 0, 0);
                acc[2] = __builtin_amdgcn_mfma_f32_16x16x32_bf16(af, wreg[2][kt], acc[2], 0, 0, 0);
                acc[3] = __builtin_amdgcn_mfma_f32_16x16x32_bf16(af, wreg[3][kt], acc[3], 0, 0, 0);
            }
        }
        // ---- write K-partials
        {
            const int jl = lane & 15, rg = lane >> 4;
#pragma unroll
            for (int g = 0; g < 4; ++g)
#pragma unroll
                for (int r = 0; r < 4; ++r)
                    part[w][g][rg * 4 + r][jl] = acc[g][r];
        }
        __syncthreads();

        // ---- epilogue: reduce 4 K-quarters, add XP, gates, c/h update
        {
            const int ebh = eb >> 4, eb16 = eb & 15;
            float gv[4];
#pragma unroll
            for (int g = 0; g < 4; ++g) {
                float s = part[ebh * 4 + 0][g][eb16][ej]
                        + part[ebh * 4 + 1][g][eb16][ej]
                        + part[ebh * 4 + 2][g][eb16][ej]
                        + part[ebh * 4 + 3][g][eb16][ej];
                gv[g] = s + bf2f(XP[((long)t * 32 + eb) * 4096 + g * 1024 + j0 + ej]);
            }
            float ig = 1.f / (1.f + __expf(-gv[0]));
            float fg = 1.f / (1.f + __expf(-gv[1]));
            float gg = tanhf(gv[2]);
            float og = 1.f / (1.f + __expf(-gv[3]));
            creg = fg * creg + ig * gg;
            float hn = og * tanhf(creg);
            out[((long)eb * TT + t) * HID + j0 + ej] = hn;
            hout[eb * HID + j0 + ej] = f2bf(hn);
        }

        // ---- grid barrier (monotonic arrive/go, agent-scope fences)
        __syncthreads();
        if (tid == 0) {
            __builtin_amdgcn_fence(__ATOMIC_RELEASE, "agent");
            __hip_atomic_fetch_add(&sync[0], 1, __ATOMIC_RELAXED, __HIP_MEMORY_SCOPE_AGENT);
            if (blockIdx.x == 0) {
                while (__hip_atomic_load(&sync[0], __ATOMIC_RELAXED, __HIP_MEMORY_SCOPE_AGENT)
                       < NBLK * (t + 1))
                    __builtin_amdgcn_s_sleep(1);
                __builtin_amdgcn_fence(__ATOMIC_ACQUIRE, "agent");
                __hip_atomic_store(&sync[1], t + 1, __ATOMIC_RELEASE, __HIP_MEMORY_SCOPE_AGENT);
            } else {
                while (__hip_atomic_load(&sync[1], __ATOMIC_RELAXED, __HIP_MEMORY_SCOPE_AGENT)
                       < t + 1)
                    __builtin_amdgcn_s_sleep(1);
                __builtin_amdgcn_fence(__ATOMIC_ACQUIRE, "agent");
            }
        }
        __syncthreads();
    }
}

extern "C" void kernel_launch(void* const* d_in, const int* in_sizes, int n_in,
                              void* d_out, int out_size, void* d_ws, size_t ws_size,
                              hipStream_t stream)
{
    const float* x   = (const float*)d_in[0];
    const float* Wih = (const float*)d_in[1];
    const float* Whh = (const float*)d_in[2];
    const float* bih = (const float*)d_in[3];
    const float* bhh = (const float*)d_in[4];
    float* out = (float*)d_out;

    char* ws = (char*)d_ws;
    size_t off = 0;
    auto alloc = [&](size_t bytes) {
        char* p = ws + off;
        off = (off + bytes + 255) & ~(size_t)255;
        return p;
    };
    unsigned short* x_bf   = (unsigned short*)alloc((size_t)BB * TT * VOC * 2);
    unsigned short* wih_bf = (unsigned short*)alloc((size_t)G4 * VOC * 2);
    unsigned short* whh_bf = (unsigned short*)alloc((size_t)G4 * HID * 2);
    unsigned short* xp     = (unsigned short*)alloc((size_t)TT * BB * G4 * 2);
    unsigned short* hbuf0  = (unsigned short*)alloc((size_t)BB * HID * 2);
    unsigned short* hbuf1  = (unsigned short*)alloc((size_t)BB * HID * 2);
    int* syncb             = (int*)alloc(256);

    // conversions to bf16
    int n4x = BB * TT * VOC / 4;
    cvt_f32_bf16<<<(n4x + 255) / 256, 256, 0, stream>>>(x, x_bf, n4x);
    int n4w = G4 * VOC / 4;
    cvt_f32_bf16<<<(n4w + 255) / 256, 256, 0, stream>>>(Wih, wih_bf, n4w);
    cvt_f32_bf16<<<(n4w + 255) / 256, 256, 0, stream>>>(Whh, whh_bf, n4w);

    // x_proj big GEMM (adds both biases, relayouts to [T][B][4H])
    gemm_xproj<<<4096, 256, 0, stream>>>(x_bf, wih_bf, bih, bhh, xp);

    // init recurrent state + barrier counters (ws is re-poisoned every launch)
    hipMemsetAsync(hbuf0, 0, (size_t)BB * HID * 2, stream);
    hipMemsetAsync(syncb, 0, 256, stream);

    // persistent scan: one launch, 512 internal steps, grid barrier per step
    lstm_scan<<<NBLK, 512, 0, stream>>>(whh_bf, xp, hbuf0, hbuf1, out, syncb);
}

// Round 3
// 3591.699 us; speedup vs baseline: 2.2199x; 1.1665x over previous
//
#include <hip/hip_runtime.h>
#include <hip/hip_bf16.h>
#include <stdint.h>

#define HID 1024
#define VOC 1024
#define BB  32
#define TT  512
#define G4  4096   // 4*HID
#define NBLK 64

typedef float f32x4 __attribute__((ext_vector_type(4)));
typedef short bf16x8 __attribute__((ext_vector_type(8)));
typedef unsigned short u16x8 __attribute__((ext_vector_type(8)));

static __device__ __forceinline__ unsigned short f2bf(float f) {
    union { float f; unsigned u; } v; v.f = f;
    unsigned r = (v.u + 0x7FFFu + ((v.u >> 16) & 1u)) >> 16;  // RTNE
    return (unsigned short)r;
}
static __device__ __forceinline__ float bf2f(unsigned short s) {
    union { unsigned u; float f; } v; v.u = ((unsigned)s) << 16;
    return v.f;
}

// ---------------- f32 -> bf16 conversion, 4 elems/thread ----------------
__global__ void cvt_f32_bf16(const float* __restrict__ in,
                             unsigned short* __restrict__ out, int n4) {
    int i = blockIdx.x * blockDim.x + threadIdx.x;
    if (i >= n4) return;
    float4 v = ((const float4*)in)[i];
    ushort4 o;
    o.x = f2bf(v.x); o.y = f2bf(v.y); o.z = f2bf(v.z); o.w = f2bf(v.w);
    ((ushort4*)out)[i] = o;
}

// ---------------- Phase 1: x_proj GEMM ----------------
// XP[t][b][n] = sum_k x[b][t][k]*W_ih[n][k] + b_ih[n] + b_hh[n], bf16,
// relaid out to [T][B][4H] so the scan reads contiguous per-step chunks.
__global__ __launch_bounds__(256) void gemm_xproj(
    const unsigned short* __restrict__ A, const unsigned short* __restrict__ W,
    const float* __restrict__ bih, const float* __restrict__ bhh,
    unsigned short* __restrict__ XP)
{
    __shared__ unsigned short As[128 * 64];
    __shared__ unsigned short Bs[128 * 64];
    const int tid  = threadIdx.x;
    const int lane = tid & 63;
    const int wid  = tid >> 6;
    const int mt = blockIdx.x & 127;   // 128 M-tiles
    const int nt = blockIdx.x >> 7;    // 32  N-tiles
    const long m0 = (long)mt * 128;
    const long n0 = (long)nt * 128;

    const int wr = wid >> 1, wc = wid & 1;
    const int rl = lane & 15;
    const int kl = (lane >> 4) * 8;

    f32x4 acc[4][4] = {};

    for (int kt = 0; kt < 16; ++kt) {
#pragma unroll
        for (int it = 0; it < 4; ++it) {
            int slot = it * 256 + tid;
            int r = slot >> 3, c8 = slot & 7;
            const unsigned short* ga = A + (m0 + r) * 1024 + kt * 64 + c8 * 8;
            const unsigned short* gb = W + (n0 + r) * 1024 + kt * 64 + c8 * 8;
            char* la = (char*)As + (it * 256 + wid * 64) * 16;
            char* lb = (char*)Bs + (it * 256 + wid * 64) * 16;
            __builtin_amdgcn_global_load_lds(
                (const __attribute__((address_space(1))) void*)ga,
                (__attribute__((address_space(3))) void*)la, 16, 0, 0);
            __builtin_amdgcn_global_load_lds(
                (const __attribute__((address_space(1))) void*)gb,
                (__attribute__((address_space(3))) void*)lb, 16, 0, 0);
        }
        __syncthreads();
#pragma unroll
        for (int kk = 0; kk < 2; ++kk) {
            bf16x8 af[4], bfr[4];
#pragma unroll
            for (int i = 0; i < 4; ++i) {
                int ar = wr * 64 + i * 16 + rl;
                int br = wc * 64 + i * 16 + rl;
                af[i]  = *(const bf16x8*)(As + ar * 64 + kk * 32 + kl);
                bfr[i] = *(const bf16x8*)(Bs + br * 64 + kk * 32 + kl);
            }
#pragma unroll
            for (int i = 0; i < 4; ++i)
#pragma unroll
                for (int j = 0; j < 4; ++j)
                    acc[i][j] = __builtin_amdgcn_mfma_f32_16x16x32_bf16(
                        af[i], bfr[j], acc[i][j], 0, 0, 0);
        }
        __syncthreads();
    }
    // epilogue: m-row = b*512+t  ->  XP row = t*32+b  (relayout)
#pragma unroll
    for (int i = 0; i < 4; ++i)
#pragma unroll
        for (int j = 0; j < 4; ++j)
#pragma unroll
            for (int r = 0; r < 4; ++r) {
                long row = m0 + wr * 64 + i * 16 + (lane >> 4) * 4 + r;
                long col = n0 + wc * 64 + j * 16 + (lane & 15);
                long orow = (row & 511) * 32 + (row >> 9);
                float v = acc[i][j][r] + bih[col] + bhh[col];
                XP[orow * 4096 + col] = f2bf(v);
            }
}

// ---------------- Phase 2: persistent scan over all 512 timesteps ----------------
// 64 blocks x 512 threads (8 waves), 1 block/CU, all co-resident.
// Block owns hidden slice j0=blockIdx.x*16 across all 4 gates.
// Wave w=(bh,kq): batch half, K quarter; A-frag read DIRECT global->reg
// (each h byte read once per block; no LDS staging). W_hh lives in 128 VGPRs.
// Decentralized barrier: per-block flags (64B apart), monotonic t+1 values;
// wave 0's 64 lanes poll all 64 flags with one load. XP software-pipelined
// one step ahead. out-stores fired after the flag store (off critical path).
__global__ __launch_bounds__(512, 2) void lstm_scan(
    const unsigned short* __restrict__ Whh,   // [4096][1024] bf16
    const unsigned short* __restrict__ XP,    // [512][32][4096] bf16
    unsigned short* __restrict__ h0,          // [32][1024] bf16 (zeroed)
    unsigned short* __restrict__ h1,          // [32][1024] bf16
    float* __restrict__ out,                  // [32][512][1024] f32
    int* __restrict__ flags)                  // [64*16] ints (zeroed)
{
    __shared__ float part[8][4][16][17];      // +1 pad: conflict-free reduce

    const int tid  = threadIdx.x;
    const int lane = tid & 63;
    const int w    = tid >> 6;     // wave 0..7
    const int bh   = w >> 2;       // batch half
    const int kq   = w & 3;        // K quarter
    const int j0   = blockIdx.x * 16;

    // ---- W_hh -> registers (once): col j0+(lane&15), k = kq*256+kt*32+(lane>>4)*8
    bf16x8 wreg[4][8];
    {
        const int nl = lane & 15, kl = (lane >> 4) * 8;
#pragma unroll
        for (int g = 0; g < 4; ++g) {
            const unsigned short* wr =
                Whh + (long)(g * 1024 + j0 + nl) * 1024 + kq * 256 + kl;
#pragma unroll
            for (int kt = 0; kt < 8; ++kt)
                wreg[g][kt] = *(const bf16x8*)(wr + kt * 32);
        }
    }

    // A-frag address: row = bh*16+(lane&15), k base = kq*256+(lane>>4)*8
    const int  arow  = bh * 16 + (lane & 15);
    const long abase = (long)arow * 1024 + kq * 256 + (lane >> 4) * 8;

    // epilogue identity: thread owns (eb, j0+ej); c state in register
    const int eb = tid >> 4;       // batch 0..31
    const int ej = tid & 15;
    const int ebh = eb >> 4, eb16 = eb & 15;
    float creg = 0.f;

    // XP pipeline: prefetch step 0
    unsigned short xpr[4];
#pragma unroll
    for (int g = 0; g < 4; ++g)
        xpr[g] = XP[(long)eb * 4096 + g * 1024 + j0 + ej];

    for (int t = 0; t < TT; ++t) {
        const unsigned short* hin = (t & 1) ? h1 : h0;
        unsigned short* hout      = (t & 1) ? h0 : h1;

        // ---- wait for all blocks to have published h(t) (flags >= t)
        if (w == 0) {
            if (t > 0) {
                while (__hip_atomic_load(&flags[lane << 4], __ATOMIC_RELAXED,
                                         __HIP_MEMORY_SCOPE_AGENT) < t)
                    __builtin_amdgcn_s_sleep(2);
            }
            __builtin_amdgcn_fence(__ATOMIC_ACQUIRE, "agent");
        }
        __syncthreads();

        // ---- A-frags direct from global (L2/L3), then 8x4 MFMAs
        bf16x8 af[8];
        {
            const unsigned short* ha = hin + abase;
#pragma unroll
            for (int kt = 0; kt < 8; ++kt)
                af[kt] = *(const bf16x8*)(ha + kt * 32);
        }
        f32x4 acc[4] = {};
#pragma unroll
        for (int kt = 0; kt < 8; ++kt) {
            acc[0] = __builtin_amdgcn_mfma_f32_16x16x32_bf16(af[kt], wreg[0][kt], acc[0], 0, 0, 0);
            acc[1] = __builtin_amdgcn_mfma_f32_16x16x32_bf16(af[kt], wreg[1][kt], acc[1], 0, 0, 0);
            acc[2] = __builtin_amdgcn_mfma_f32_16x16x32_bf16(af[kt], wreg[2][kt], acc[2], 0, 0, 0);
            acc[3] = __builtin_amdgcn_mfma_f32_16x16x32_bf16(af[kt], wreg[3][kt], acc[3], 0, 0, 0);
        }

        // ---- prefetch next step's XP (used next iteration; latency hidden)
        unsigned short xpn[4];
        {
            const long tn = (t + 1 < TT) ? (t + 1) : t;
#pragma unroll
            for (int g = 0; g < 4; ++g)
                xpn[g] = XP[(tn * 32 + eb) * 4096 + g * 1024 + j0 + ej];
        }

        // ---- write K-partials
        {
            const int jl = lane & 15, rg = lane >> 4;
#pragma unroll
            for (int g = 0; g < 4; ++g)
#pragma unroll
                for (int r = 0; r < 4; ++r)
                    part[w][g][rg * 4 + r][jl] = acc[g][r];
        }
        __syncthreads();

        // ---- epilogue: reduce 4 K-quarters, add XP, gates, c/h update
        float hn;
        {
            float gv[4];
#pragma unroll
            for (int g = 0; g < 4; ++g) {
                float s = part[ebh * 4 + 0][g][eb16][ej]
                        + part[ebh * 4 + 1][g][eb16][ej]
                        + part[ebh * 4 + 2][g][eb16][ej]
                        + part[ebh * 4 + 3][g][eb16][ej];
                gv[g] = s + bf2f(xpr[g]);
            }
            float ig = 1.f / (1.f + __expf(-gv[0]));
            float fg = 1.f / (1.f + __expf(-gv[1]));
            float gg = tanhf(gv[2]);
            float og = 1.f / (1.f + __expf(-gv[3]));
            creg = fg * creg + ig * gg;
            hn = og * tanhf(creg);
            hout[eb * HID + j0 + ej] = f2bf(hn);
        }
        __syncthreads();   // all waves' h stores drained (vmcnt(0) at barrier)

        // ---- publish h(t+1): one release fence + own flag store
        if (tid == 0) {
            __builtin_amdgcn_fence(__ATOMIC_RELEASE, "agent");
            __hip_atomic_store(&flags[blockIdx.x << 4], t + 1, __ATOMIC_RELAXED,
                               __HIP_MEMORY_SCOPE_AGENT);
        }

        // ---- out store AFTER flag (never on the inter-block critical path)
        out[((long)eb * TT + t) * HID + j0 + ej] = hn;

        // rotate XP pipeline
#pragma unroll
        for (int g = 0; g < 4; ++g) xpr[g] = xpn[g];
    }
}

extern "C" void kernel_launch(void* const* d_in, const int* in_sizes, int n_in,
                              void* d_out, int out_size, void* d_ws, size_t ws_size,
                              hipStream_t stream)
{
    const float* x   = (const float*)d_in[0];
    const float* Wih = (const float*)d_in[1];
    const float* Whh = (const float*)d_in[2];
    const float* bih = (const float*)d_in[3];
    const float* bhh = (const float*)d_in[4];
    float* out = (float*)d_out;

    char* ws = (char*)d_ws;
    size_t off = 0;
    auto alloc = [&](size_t bytes) {
        char* p = ws + off;
        off = (off + bytes + 255) & ~(size_t)255;
        return p;
    };
    unsigned short* x_bf   = (unsigned short*)alloc((size_t)BB * TT * VOC * 2);
    unsigned short* wih_bf = (unsigned short*)alloc((size_t)G4 * VOC * 2);
    unsigned short* whh_bf = (unsigned short*)alloc((size_t)G4 * HID * 2);
    unsigned short* xp     = (unsigned short*)alloc((size_t)TT * BB * G4 * 2);
    unsigned short* hbuf0  = (unsigned short*)alloc((size_t)BB * HID * 2);
    unsigned short* hbuf1  = (unsigned short*)alloc((size_t)BB * HID * 2);
    int* flags             = (int*)alloc(NBLK * 16 * sizeof(int));

    // conversions to bf16
    int n4x = BB * TT * VOC / 4;
    cvt_f32_bf16<<<(n4x + 255) / 256, 256, 0, stream>>>(x, x_bf, n4x);
    int n4w = G4 * VOC / 4;
    cvt_f32_bf16<<<(n4w + 255) / 256, 256, 0, stream>>>(Wih, wih_bf, n4w);
    cvt_f32_bf16<<<(n4w + 255) / 256, 256, 0, stream>>>(Whh, whh_bf, n4w);

    // x_proj big GEMM (adds both biases, relayouts to [T][B][4H])
    gemm_xproj<<<4096, 256, 0, stream>>>(x_bf, wih_bf, bih, bhh, xp);

    // init recurrent state + flags (ws is re-poisoned before every launch)
    hipMemsetAsync(hbuf0, 0, (size_t)BB * HID * 2, stream);
    hipMemsetAsync(flags, 0, NBLK * 16 * sizeof(int), stream);

    // persistent scan: one launch, 512 internal steps, flag barrier per step
    lstm_scan<<<NBLK, 512, 0, stream>>>(whh_bf, xp, hbuf0, hbuf1, out, flags);
}